// Round 1
// baseline (357.187 us; speedup 1.0000x reference)
//
#include <hip/hip_runtime.h>
#include <math.h>

#define NFEAT 128
#define NGRAPHS 2048

// Kernel 1: segment boundaries from the sorted batch array.
// starts[g] = first index i with batch[i] >= g; starts[NGRAPHS] = n.
// Every element of starts[0..NGRAPHS] is written every call (ws is re-poisoned).
__global__ void find_starts_kernel(const int* __restrict__ batch, int n,
                                   int* __restrict__ starts) {
    int i = blockIdx.x * blockDim.x + threadIdx.x;
    if (i >= n) return;
    int b = batch[i];
    int prev = (i == 0) ? -1 : batch[i - 1];
    for (int g = prev + 1; g <= b; ++g) starts[g] = i;
    if (i == n - 1) {
        for (int g = b + 1; g <= NGRAPHS; ++g) starts[g] = n;
    }
}

// Kernel 2: one block per graph. Online (flash-style) softmax-weighted sum
// over the graph's contiguous node range, single pass over x.
// Layout: lane = tid&31 owns features [4*lane, 4*lane+4) via float4 loads
// (16 B/lane -> perfectly coalesced 1 KiB per wave); rg = tid>>5 strides rows.
__global__ __launch_bounds__(256) void pool_kernel(
    const float* __restrict__ x, const int* __restrict__ starts,
    const float* __restrict__ p_ptr, const float* __restrict__ beta_ptr,
    float* __restrict__ out) {
    const int g = blockIdx.x;
    const int s = starts[g];
    const int e = starts[g + 1];
    const int cnt = e - s;
    const float p = p_ptr[0];
    const float beta = beta_ptr[0];

    const int lane = threadIdx.x & 31;  // feature-quad index (0..31)
    const int rg = threadIdx.x >> 5;    // row group (0..7)

    float m[4], d[4], num[4];
#pragma unroll
    for (int j = 0; j < 4; ++j) {
        m[j] = -INFINITY;
        d[j] = 0.0f;
        num[j] = 0.0f;
    }

    const float* __restrict__ xg = x + (size_t)s * NFEAT;
    for (int r = rg; r < cnt; r += 8) {
        const float4 v = *(const float4*)(xg + (size_t)r * NFEAT + lane * 4);
        float vals[4] = {v.x, v.y, v.z, v.w};
#pragma unroll
        for (int j = 0; j < 4; ++j) {
            float l = p * vals[j];
            float mn = fmaxf(m[j], l);
            float sc = __expf(m[j] - mn);  // == 1 when max unchanged; 0 first iter
            float t = __expf(l - mn);
            d[j] = d[j] * sc + t;
            num[j] = num[j] * sc + vals[j] * t;
            m[j] = mn;
        }
    }

    // Combine the 8 row-group partial softmax states per feature via LDS.
    __shared__ float sm[8][NFEAT];
    __shared__ float sd[8][NFEAT];
    __shared__ float sn[8][NFEAT];
#pragma unroll
    for (int j = 0; j < 4; ++j) {
        sm[rg][lane * 4 + j] = m[j];
        sd[rg][lane * 4 + j] = d[j];
        sn[rg][lane * 4 + j] = num[j];
    }
    __syncthreads();

    if (threadIdx.x < NFEAT) {
        const int f = threadIdx.x;
        float M = sm[0][f], D = sd[0][f], Nm = sn[0][f];
#pragma unroll
        for (int k = 1; k < 8; ++k) {
            float m2 = sm[k][f];
            float Mn = fmaxf(M, m2);
            float s1 = __expf(M - Mn);
            float s2 = __expf(m2 - Mn);
            D = D * s1 + sd[k][f] * s2;
            Nm = Nm * s1 + sn[k][f] * s2;
            M = Mn;
        }
        float n = (float)cnt;
        float rescale = n / (1.0f + beta * (n - 1.0f));
        out[(size_t)g * NFEAT + f] = (Nm / D) * rescale;
    }
}

extern "C" void kernel_launch(void* const* d_in, const int* in_sizes, int n_in,
                              void* d_out, int out_size, void* d_ws, size_t ws_size,
                              hipStream_t stream) {
    const float* x = (const float*)d_in[0];
    const int* batch = (const int*)d_in[1];
    const float* p = (const float*)d_in[2];
    const float* beta = (const float*)d_in[3];
    float* out = (float*)d_out;
    int* starts = (int*)d_ws;  // NGRAPHS+1 ints

    const int n = in_sizes[0] / NFEAT;  // 500000

    find_starts_kernel<<<(n + 255) / 256, 256, 0, stream>>>(batch, n, starts);
    pool_kernel<<<NGRAPHS, 256, 0, stream>>>(x, starts, p, beta, out);
}

// Round 2
// 355.532 us; speedup vs baseline: 1.0047x; 1.0047x over previous
//
#include <hip/hip_runtime.h>
#include <math.h>

#define NFEAT 128
#define NGRAPHS 2048

// Kernel 1: segment boundaries from the sorted batch array.
// starts[g] = first index i with batch[i] >= g; starts[NGRAPHS] = n.
// Every element of starts[0..NGRAPHS] is written every call (ws is re-poisoned).
__global__ void find_starts_kernel(const int* __restrict__ batch, int n,
                                   int* __restrict__ starts) {
    int i = blockIdx.x * blockDim.x + threadIdx.x;
    if (i >= n) return;
    int b = batch[i];
    int prev = (i == 0) ? -1 : batch[i - 1];
    for (int g = prev + 1; g <= b; ++g) starts[g] = i;
    if (i == n - 1) {
        for (int g = b + 1; g <= NGRAPHS; ++g) starts[g] = n;
    }
}

// Online-softmax update for one float4 (4 features owned by this lane).
__device__ __forceinline__ void update4(const float4& v, float p,
                                        float* m, float* d, float* num) {
    float vals[4] = {v.x, v.y, v.z, v.w};
#pragma unroll
    for (int j = 0; j < 4; ++j) {
        float l = p * vals[j];
        float mn = fmaxf(m[j], l);
        float sc = __expf(m[j] - mn);  // 1 when max unchanged; 0 on first row
        float t = __expf(l - mn);
        d[j] = d[j] * sc + t;
        num[j] = num[j] * sc + vals[j] * t;
        m[j] = mn;
    }
}

// Kernel 2: one block per graph; single pass over the graph's contiguous rows.
// lane = tid&31 owns features [4*lane, 4*lane+4) (float4, 16 B/lane coalesced);
// rg = tid>>5 strides rows. Two rows per iteration + prefetch of the next two
// -> up to 4 dwordx4 loads in flight per wave (vs 1 in the naive loop).
__global__ __launch_bounds__(256) void pool_kernel(
    const float* __restrict__ x, const int* __restrict__ starts,
    const float* __restrict__ p_ptr, const float* __restrict__ beta_ptr,
    float* __restrict__ out) {
    const int g = blockIdx.x;
    const int s = starts[g];
    const int e = starts[g + 1];
    const int cnt = e - s;
    const float p = p_ptr[0];
    const float beta = beta_ptr[0];

    const int lane = threadIdx.x & 31;  // feature-quad index (0..31)
    const int rg = threadIdx.x >> 5;    // row group (0..7)

    float m[4], d[4], num[4];
#pragma unroll
    for (int j = 0; j < 4; ++j) {
        m[j] = -INFINITY;
        d[j] = 0.0f;
        num[j] = 0.0f;
    }

    const float* __restrict__ bp = x + (size_t)s * NFEAT + lane * 4;

    int r = rg;
    bool h0 = r < cnt;
    bool h1 = (r + 8) < cnt;
    float4 c0 = make_float4(0.f, 0.f, 0.f, 0.f);
    float4 c1 = c0;
    if (h0) c0 = *(const float4*)(bp + (size_t)r * NFEAT);
    if (h1) c1 = *(const float4*)(bp + (size_t)(r + 8) * NFEAT);

    while (h0) {
        const int rn = r + 16;
        const bool hn0 = rn < cnt;
        const bool hn1 = (rn + 8) < cnt;
        float4 n0 = make_float4(0.f, 0.f, 0.f, 0.f);
        float4 n1 = n0;
        if (hn0) n0 = *(const float4*)(bp + (size_t)rn * NFEAT);
        if (hn1) n1 = *(const float4*)(bp + (size_t)(rn + 8) * NFEAT);

        update4(c0, p, m, d, num);
        if (h1) update4(c1, p, m, d, num);

        c0 = n0; c1 = n1; h0 = hn0; h1 = hn1; r = rn;
    }

    // Combine the 8 row-group partial softmax states per feature via LDS.
    __shared__ float sm[8][NFEAT];
    __shared__ float sd[8][NFEAT];
    __shared__ float sn[8][NFEAT];
#pragma unroll
    for (int j = 0; j < 4; ++j) {
        sm[rg][lane * 4 + j] = m[j];
        sd[rg][lane * 4 + j] = d[j];
        sn[rg][lane * 4 + j] = num[j];
    }
    __syncthreads();

    if (threadIdx.x < NFEAT) {
        const int f = threadIdx.x;
        float M = sm[0][f], D = sd[0][f], Nm = sn[0][f];
#pragma unroll
        for (int k = 1; k < 8; ++k) {
            float m2 = sm[k][f];
            float Mn = fmaxf(M, m2);
            float s1 = __expf(M - Mn);
            float s2 = __expf(m2 - Mn);
            D = D * s1 + sd[k][f] * s2;
            Nm = Nm * s1 + sn[k][f] * s2;
            M = Mn;
        }
        float n = (float)cnt;
        float rescale = n / (1.0f + beta * (n - 1.0f));
        out[(size_t)g * NFEAT + f] = (Nm / D) * rescale;
    }
}

extern "C" void kernel_launch(void* const* d_in, const int* in_sizes, int n_in,
                              void* d_out, int out_size, void* d_ws, size_t ws_size,
                              hipStream_t stream) {
    const float* x = (const float*)d_in[0];
    const int* batch = (const int*)d_in[1];
    const float* p = (const float*)d_in[2];
    const float* beta = (const float*)d_in[3];
    float* out = (float*)d_out;
    int* starts = (int*)d_ws;  // NGRAPHS+1 ints

    const int n = in_sizes[0] / NFEAT;  // 500000

    find_starts_kernel<<<(n + 255) / 256, 256, 0, stream>>>(batch, n, starts);
    pool_kernel<<<NGRAPHS, 256, 0, stream>>>(x, starts, p, beta, out);
}